// Round 2
// baseline (1347.487 us; speedup 1.0000x reference)
//
#include <hip/hip_runtime.h>
#include <hip/hip_bf16.h>
#include <cstdint>
#include <cstddef>

#define NN 65536
#define EE 131072
#define GG 4096
#define HH 128
#define DD 64
#define INF_ 321
#define ITEMS 50000
#define ITEMSP 50048   // padded to multiple of 64

typedef __attribute__((ext_vector_type(8))) short bf16x8;
typedef __attribute__((ext_vector_type(4))) float f32x4;

// ---------------- embedding gather: build X[N][321] ----------------
__global__ void k_embed(const int* __restrict__ cat, const int* __restrict__ sub,
                        const int* __restrict__ el, const int* __restrict__ br,
                        const int* __restrict__ pid, const float* __restrict__ price,
                        const float* __restrict__ ecat, const float* __restrict__ esub,
                        const float* __restrict__ eel, const float* __restrict__ ebr,
                        const float* __restrict__ eitem, float* __restrict__ X) {
    int tid = threadIdx.x;
    int n = blockIdx.x * 4 + (tid >> 6);
    int l = tid & 63;
    float* xr = X + (size_t)n * INF_;
    if (l == 0) xr[0] = price[n];
    xr[1 + l]   = ecat[(size_t)cat[n] * DD + l];
    xr[65 + l]  = esub[(size_t)sub[n] * DD + l];
    xr[129 + l] = eel[(size_t)el[n] * DD + l];
    xr[193 + l] = ebr[(size_t)br[n] * DD + l];
    xr[257 + l] = eitem[(size_t)pid[n] * DD + l];
}

// ---------------- generic tiled fp32 GEMM: C = A(MxK) @ W(NoutxK)^T + bias ----------------
#define BM 128
#define BN 128
#define BKC 32
__launch_bounds__(256)
__global__ void gemm_bt(const float* __restrict__ A, const float* __restrict__ W,
                        const float* __restrict__ bias, float* __restrict__ C,
                        int M, int Nout, int K, int act) {
    __shared__ float As[BKC][BM + 4];
    __shared__ float Bs[BKC][BN + 4];
    int tid = threadIdx.x;
    int m0 = blockIdx.x * BM;
    int n0 = blockIdx.y * BN;
    int tx = tid & 15, ty = tid >> 4;
    int sr = tid >> 1;
    int sk = (tid & 1) * 16;
    float acc[8][8] = {};
    const bool vec = ((K & 3) == 0);

    for (int k0 = 0; k0 < K; k0 += BKC) {
        {
            const float* Ar = A + (size_t)(m0 + sr) * K;
            if (vec) {
                #pragma unroll
                for (int c = 0; c < 16; c += 4) {
                    int k = k0 + sk + c;
                    float4 v = make_float4(0.f, 0.f, 0.f, 0.f);
                    if (k < K) v = *(const float4*)(Ar + k);
                    As[sk + c + 0][sr] = v.x;
                    As[sk + c + 1][sr] = v.y;
                    As[sk + c + 2][sr] = v.z;
                    As[sk + c + 3][sr] = v.w;
                }
            } else {
                #pragma unroll
                for (int c = 0; c < 16; ++c) {
                    int k = k0 + sk + c;
                    As[sk + c][sr] = (k < K) ? Ar[k] : 0.f;
                }
            }
        }
        {
            int wr = n0 + sr;
            bool ok = (wr < Nout);
            const float* Wr = W + (size_t)wr * K;
            if (vec) {
                #pragma unroll
                for (int c = 0; c < 16; c += 4) {
                    int k = k0 + sk + c;
                    float4 v = make_float4(0.f, 0.f, 0.f, 0.f);
                    if (ok && k < K) v = *(const float4*)(Wr + k);
                    Bs[sk + c + 0][sr] = v.x;
                    Bs[sk + c + 1][sr] = v.y;
                    Bs[sk + c + 2][sr] = v.z;
                    Bs[sk + c + 3][sr] = v.w;
                }
            } else {
                #pragma unroll
                for (int c = 0; c < 16; ++c) {
                    int k = k0 + sk + c;
                    Bs[sk + c][sr] = (ok && k < K) ? Wr[k] : 0.f;
                }
            }
        }
        __syncthreads();
        #pragma unroll
        for (int k = 0; k < BKC; ++k) {
            float4 a0 = *(const float4*)&As[k][ty * 8];
            float4 a1 = *(const float4*)&As[k][ty * 8 + 4];
            float4 b0 = *(const float4*)&Bs[k][tx * 8];
            float4 b1 = *(const float4*)&Bs[k][tx * 8 + 4];
            float a[8] = {a0.x, a0.y, a0.z, a0.w, a1.x, a1.y, a1.z, a1.w};
            float b[8] = {b0.x, b0.y, b0.z, b0.w, b1.x, b1.y, b1.z, b1.w};
            #pragma unroll
            for (int i = 0; i < 8; ++i) {
                #pragma unroll
                for (int j = 0; j < 8; ++j) acc[i][j] += a[i] * b[j];
            }
        }
        __syncthreads();
    }

    #pragma unroll
    for (int i = 0; i < 8; ++i) {
        int row = m0 + ty * 8 + i;
        float* Cr = C + (size_t)row * Nout;
        #pragma unroll
        for (int j = 0; j < 8; j += 4) {
            int col = n0 + tx * 8 + j;
            if (col < Nout) {
                float4 bv = *(const float4*)&bias[col];
                float4 o;
                o.x = acc[i][j + 0] + bv.x;
                o.y = acc[i][j + 1] + bv.y;
                o.z = acc[i][j + 2] + bv.z;
                o.w = acc[i][j + 3] + bv.w;
                if (act) {
                    o.x = fmaxf(o.x, 0.f); o.y = fmaxf(o.y, 0.f);
                    o.z = fmaxf(o.z, 0.f); o.w = fmaxf(o.w, 0.f);
                }
                *(float4*)&Cr[col] = o;
            }
        }
    }
}

// ---------------- edge scatter: msg[dst] += h[src]; cnt[dst] += 1 ----------------
__global__ void k_scatter(const float* __restrict__ h, const int* __restrict__ edge,
                          float* __restrict__ msg, float* __restrict__ cnt) {
    int tid = threadIdx.x;
    int e = blockIdx.x * 2 + (tid >> 7);
    int j = tid & 127;
    int s = edge[e];
    int d = edge[EE + e];
    atomicAdd(&msg[(size_t)d * HH + j], h[(size_t)s * HH + j]);
    if (j == 0) atomicAdd(&cnt[d], 1.0f);
}

// ---------------- m = msg / max(cnt,1) ----------------
__global__ void k_prep(float* __restrict__ msg, const float* __restrict__ cnt) {
    int i = blockIdx.x * 256 + threadIdx.x;
    int n = i >> 7;
    msg[i] = msg[i] / fmaxf(cnt[n], 1.0f);
}

// ---------------- GRU combine: h = (1-z)*n + z*h ----------------
__global__ void k_combine(const float* __restrict__ gi, const float* __restrict__ gh,
                          float* __restrict__ h) {
    int i = blockIdx.x * 256 + threadIdx.x;
    int n = i >> 7;
    int j = i & 127;
    size_t b = (size_t)n * 384;
    float gir = gi[b + j], giz = gi[b + 128 + j], gin = gi[b + 256 + j];
    float ghr = gh[b + j], ghz = gh[b + 128 + j], ghn = gh[b + 256 + j];
    float hv = h[i];
    float r = 1.f / (1.f + expf(-(gir + ghr)));
    float z = 1.f / (1.f + expf(-(giz + ghz)));
    float nn = tanhf(gin + r * ghn);
    h[i] = (1.f - z) * nn + z * hv;
}

// ---------------- gate scalar ----------------
__global__ void k_gatevec(const float* __restrict__ g1, const float* __restrict__ Wg2,
                          const float* __restrict__ bg2, float* __restrict__ gate) {
    int tid = threadIdx.x;
    int n = blockIdx.x * 4 + (tid >> 6);
    int l = tid & 63;
    const float* gr = g1 + (size_t)n * HH;
    float v = Wg2[l] * gr[l] + Wg2[64 + l] * gr[64 + l];
    #pragma unroll
    for (int o = 32; o > 0; o >>= 1) v += __shfl_down(v, o);
    if (l == 0) gate[n] = v + bg2[0];
}

// ---------------- segment softmax + weighted pool ----------------
__global__ void k_pool(const float* __restrict__ gate, const float* __restrict__ h,
                       float* __restrict__ pooled) {
    int g = blockIdx.x;
    int t = threadIdx.x;  // 0..127
    __shared__ float sg[16];
    if (t < 16) sg[t] = gate[g * 16 + t];
    __syncthreads();
    float mx = -1e30f;
    #pragma unroll
    for (int i = 0; i < 16; ++i) mx = fmaxf(mx, sg[i]);
    float a[16];
    float den = 0.f;
    #pragma unroll
    for (int i = 0; i < 16; ++i) { a[i] = expf(sg[i] - mx); den += a[i]; }
    float inv = 1.f / den;
    float acc = 0.f;
    #pragma unroll
    for (int i = 0; i < 16; ++i)
        acc += a[i] * inv * h[((size_t)(g * 16 + i)) * HH + t];
    pooled[(size_t)g * HH + t] = acc;
}

// ---------------- fp32 -> bf16 hi/lo split ----------------
__global__ void k_cvt_pair(const float* __restrict__ src, unsigned short* __restrict__ hi,
                           unsigned short* __restrict__ lo, int n_valid, int n_total) {
    int i = blockIdx.x * 256 + threadIdx.x;
    if (i >= n_total) return;
    float x = (i < n_valid) ? src[i] : 0.f;
    __hip_bfloat16 h = __float2bfloat16(x);
    float hf = __bfloat162float(h);
    __hip_bfloat16 l = __float2bfloat16(x - hf);
    hi[i] = *reinterpret_cast<unsigned short*>(&h);
    lo[i] = *reinterpret_cast<unsigned short*>(&l);
}

// ---------------- FC GEMM via split-bf16 MFMA: out = pooled @ Wfc^T + bfc ----------------
// grid: (ITEMSP/64, 8), block 256 (4 waves). Each wave owns 16 output cols,
// keeps its Wfc hi/lo fragments in registers, loops over 32 M-tiles of 16 rows.
__launch_bounds__(256)
__global__ void k_fc(const unsigned short* __restrict__ Whi, const unsigned short* __restrict__ Wlo,
                     const unsigned short* __restrict__ phi, const unsigned short* __restrict__ plo,
                     const float* __restrict__ bfc, float* __restrict__ out) {
    int tid = threadIdx.x;
    int w = tid >> 6;          // wave 0..3
    int l = tid & 63;
    int n = blockIdx.x * 64 + w * 16 + (l & 15);   // output col (padded space)
    int koff = (l >> 4) * 8;

    bf16x8 bh[4], bl[4];
    const unsigned short* Wr  = Whi + (size_t)n * HH;
    const unsigned short* Wr2 = Wlo + (size_t)n * HH;
    #pragma unroll
    for (int kc = 0; kc < 4; ++kc) {
        bh[kc] = *(const bf16x8*)(Wr  + kc * 32 + koff);
        bl[kc] = *(const bf16x8*)(Wr2 + kc * 32 + koff);
    }
    float bias = (n < ITEMS) ? bfc[n] : 0.f;

    int mt0 = blockIdx.y * 32;
    for (int mt = 0; mt < 32; ++mt) {
        int m0 = (mt0 + mt) * 16;
        const unsigned short* pr  = phi + (size_t)(m0 + (l & 15)) * HH + koff;
        const unsigned short* pr2 = plo + (size_t)(m0 + (l & 15)) * HH + koff;
        f32x4 acc = {0.f, 0.f, 0.f, 0.f};
        #pragma unroll
        for (int kc = 0; kc < 4; ++kc) {
            bf16x8 ah = *(const bf16x8*)(pr  + kc * 32);
            bf16x8 al = *(const bf16x8*)(pr2 + kc * 32);
            acc = __builtin_amdgcn_mfma_f32_16x16x32_bf16(ah, bh[kc], acc, 0, 0, 0);
            acc = __builtin_amdgcn_mfma_f32_16x16x32_bf16(ah, bl[kc], acc, 0, 0, 0);
            acc = __builtin_amdgcn_mfma_f32_16x16x32_bf16(al, bh[kc], acc, 0, 0, 0);
        }
        if (n < ITEMS) {
            int row = m0 + (l >> 4) * 4;
            #pragma unroll
            for (int r = 0; r < 4; ++r)
                out[(size_t)(row + r) * ITEMS + n] = acc[r] + bias;
        }
    }
}

extern "C" void kernel_launch(void* const* d_in, const int* in_sizes, int n_in,
                              void* d_out, int out_size, void* d_ws, size_t ws_size,
                              hipStream_t stream) {
    const int* category = (const int*)d_in[0];
    const int* sub_cat  = (const int*)d_in[1];
    const int* element  = (const int*)d_in[2];
    const int* brand    = (const int*)d_in[3];
    const int* pid      = (const int*)d_in[4];
    const float* price  = (const float*)d_in[5];
    const int* edge     = (const int*)d_in[6];
    const float* ecat   = (const float*)d_in[8];
    const float* esub   = (const float*)d_in[9];
    const float* eel    = (const float*)d_in[10];
    const float* ebr    = (const float*)d_in[11];
    const float* eitem  = (const float*)d_in[12];
    const float* Wm     = (const float*)d_in[13];
    const float* bm     = (const float*)d_in[14];
    const float* W_ih   = (const float*)d_in[15];
    const float* b_ih   = (const float*)d_in[16];
    const float* W_hh   = (const float*)d_in[17];
    const float* b_hh   = (const float*)d_in[18];
    const float* Wg1    = (const float*)d_in[19];
    const float* bg1    = (const float*)d_in[20];
    const float* Wg2    = (const float*)d_in[21];
    const float* bg2    = (const float*)d_in[22];
    const float* Wfc    = (const float*)d_in[23];
    const float* bfc    = (const float*)d_in[24];
    float* out = (float*)d_out;

    // workspace layout (floats)
    const size_t REG = (size_t)NN * 384;
    float* ws = (float*)d_ws;
    float* regionA = ws;                         // X (N*321) then gh (N*384)
    float* regionB = ws + REG;                   // gi (N*384); later bf16 splits
    float* hbuf    = ws + 2 * REG;               // N*128
    float* msg     = hbuf + (size_t)NN * HH;     // N*128 (msg -> m -> g1)
    float* cnt     = msg + (size_t)NN * HH;      // N
    float* gate    = cnt + NN;                   // N
    float* pooled  = gate + NN;                  // G*128

    // bf16 split buffers live in regionB (free after k_combine): 28 MB << 100 MB
    unsigned short* Whi = (unsigned short*)regionB;
    unsigned short* Wlo = Whi + (size_t)ITEMSP * HH;
    unsigned short* phi = Wlo + (size_t)ITEMSP * HH;
    unsigned short* plo = phi + (size_t)GG * HH;

    hipMemsetAsync(msg, 0, (size_t)NN * HH * sizeof(float), stream);
    hipMemsetAsync(cnt, 0, (size_t)NN * sizeof(float), stream);

    // 1. embedding gather
    k_embed<<<NN / 4, 256, 0, stream>>>(category, sub_cat, element, brand, pid, price,
                                        ecat, esub, eel, ebr, eitem, regionA);
    // 2. h = X @ Wm^T + bm
    gemm_bt<<<dim3(NN / BM, 1), 256, 0, stream>>>(regionA, Wm, bm, hbuf, NN, HH, INF_, 0);
    // 3. scatter-mean
    k_scatter<<<EE / 2, 256, 0, stream>>>(hbuf, edge, msg, cnt);
    k_prep<<<NN * HH / 256, 256, 0, stream>>>(msg, cnt);
    // 4. GRU gemms
    gemm_bt<<<dim3(NN / BM, 3), 256, 0, stream>>>(msg, W_ih, b_ih, regionB, NN, 384, HH, 0);
    gemm_bt<<<dim3(NN / BM, 3), 256, 0, stream>>>(hbuf, W_hh, b_hh, regionA, NN, 384, HH, 0);
    k_combine<<<NN * HH / 256, 256, 0, stream>>>(regionB, regionA, hbuf);
    // 5. gate MLP (g1 -> msg buffer)
    gemm_bt<<<dim3(NN / BM, 1), 256, 0, stream>>>(hbuf, Wg1, bg1, msg, NN, HH, HH, 1);
    k_gatevec<<<NN / 4, 256, 0, stream>>>(msg, Wg2, bg2, gate);
    // 6. segment softmax pooling
    k_pool<<<GG, 128, 0, stream>>>(gate, hbuf, pooled);
    // 7. split-bf16 conversions (regionB is free now)
    {
        int ntot = ITEMSP * HH;
        k_cvt_pair<<<(ntot + 255) / 256, 256, 0, stream>>>(Wfc, Whi, Wlo, ITEMS * HH, ntot);
        int ptot = GG * HH;
        k_cvt_pair<<<(ptot + 255) / 256, 256, 0, stream>>>(pooled, phi, plo, ptot, ptot);
    }
    // 8. out = pooled @ Wfc^T + bfc via MFMA
    k_fc<<<dim3(ITEMSP / 64, 8), 256, 0, stream>>>(Whi, Wlo, phi, plo, bfc, out);
}

// Round 3
// 957.143 us; speedup vs baseline: 1.4078x; 1.4078x over previous
//
#include <hip/hip_runtime.h>
#include <hip/hip_bf16.h>
#include <cstdint>
#include <cstddef>

#define NN 65536
#define EE 131072
#define GG 4096
#define HH 128
#define DD 64
#define INF_ 321
#define ITEMS 50000
#define NP 50176       // padded to multiple of 256

typedef __attribute__((ext_vector_type(8))) short bf16x8;
typedef __attribute__((ext_vector_type(4))) float f32x4;

// ---------------- embedding gather: build X[N][321] ----------------
__global__ void k_embed(const int* __restrict__ cat, const int* __restrict__ sub,
                        const int* __restrict__ el, const int* __restrict__ br,
                        const int* __restrict__ pid, const float* __restrict__ price,
                        const float* __restrict__ ecat, const float* __restrict__ esub,
                        const float* __restrict__ eel, const float* __restrict__ ebr,
                        const float* __restrict__ eitem, float* __restrict__ X) {
    int tid = threadIdx.x;
    int n = blockIdx.x * 4 + (tid >> 6);
    int l = tid & 63;
    float* xr = X + (size_t)n * INF_;
    if (l == 0) xr[0] = price[n];
    xr[1 + l]   = ecat[(size_t)cat[n] * DD + l];
    xr[65 + l]  = esub[(size_t)sub[n] * DD + l];
    xr[129 + l] = eel[(size_t)el[n] * DD + l];
    xr[193 + l] = ebr[(size_t)br[n] * DD + l];
    xr[257 + l] = eitem[(size_t)pid[n] * DD + l];
}

// ---------------- generic tiled fp32 GEMM: C = A(MxK) @ W(NoutxK)^T + bias ----------------
#define BM 128
#define BN 128
#define BKC 32
__launch_bounds__(256)
__global__ void gemm_bt(const float* __restrict__ A, const float* __restrict__ W,
                        const float* __restrict__ bias, float* __restrict__ C,
                        int M, int Nout, int K, int act) {
    __shared__ float As[BKC][BM + 4];
    __shared__ float Bs[BKC][BN + 4];
    int tid = threadIdx.x;
    int m0 = blockIdx.x * BM;
    int n0 = blockIdx.y * BN;
    int tx = tid & 15, ty = tid >> 4;
    int sr = tid >> 1;
    int sk = (tid & 1) * 16;
    float acc[8][8] = {};
    const bool vec = ((K & 3) == 0);

    for (int k0 = 0; k0 < K; k0 += BKC) {
        {
            const float* Ar = A + (size_t)(m0 + sr) * K;
            if (vec) {
                #pragma unroll
                for (int c = 0; c < 16; c += 4) {
                    int k = k0 + sk + c;
                    float4 v = make_float4(0.f, 0.f, 0.f, 0.f);
                    if (k < K) v = *(const float4*)(Ar + k);
                    As[sk + c + 0][sr] = v.x;
                    As[sk + c + 1][sr] = v.y;
                    As[sk + c + 2][sr] = v.z;
                    As[sk + c + 3][sr] = v.w;
                }
            } else {
                #pragma unroll
                for (int c = 0; c < 16; ++c) {
                    int k = k0 + sk + c;
                    As[sk + c][sr] = (k < K) ? Ar[k] : 0.f;
                }
            }
        }
        {
            int wr = n0 + sr;
            bool ok = (wr < Nout);
            const float* Wr = W + (size_t)wr * K;
            if (vec) {
                #pragma unroll
                for (int c = 0; c < 16; c += 4) {
                    int k = k0 + sk + c;
                    float4 v = make_float4(0.f, 0.f, 0.f, 0.f);
                    if (ok && k < K) v = *(const float4*)(Wr + k);
                    Bs[sk + c + 0][sr] = v.x;
                    Bs[sk + c + 1][sr] = v.y;
                    Bs[sk + c + 2][sr] = v.z;
                    Bs[sk + c + 3][sr] = v.w;
                }
            } else {
                #pragma unroll
                for (int c = 0; c < 16; ++c) {
                    int k = k0 + sk + c;
                    Bs[sk + c][sr] = (ok && k < K) ? Wr[k] : 0.f;
                }
            }
        }
        __syncthreads();
        #pragma unroll
        for (int k = 0; k < BKC; ++k) {
            float4 a0 = *(const float4*)&As[k][ty * 8];
            float4 a1 = *(const float4*)&As[k][ty * 8 + 4];
            float4 b0 = *(const float4*)&Bs[k][tx * 8];
            float4 b1 = *(const float4*)&Bs[k][tx * 8 + 4];
            float a[8] = {a0.x, a0.y, a0.z, a0.w, a1.x, a1.y, a1.z, a1.w};
            float b[8] = {b0.x, b0.y, b0.z, b0.w, b1.x, b1.y, b1.z, b1.w};
            #pragma unroll
            for (int i = 0; i < 8; ++i) {
                #pragma unroll
                for (int j = 0; j < 8; ++j) acc[i][j] += a[i] * b[j];
            }
        }
        __syncthreads();
    }

    #pragma unroll
    for (int i = 0; i < 8; ++i) {
        int row = m0 + ty * 8 + i;
        float* Cr = C + (size_t)row * Nout;
        #pragma unroll
        for (int j = 0; j < 8; j += 4) {
            int col = n0 + tx * 8 + j;
            if (col < Nout) {
                float4 bv = *(const float4*)&bias[col];
                float4 o;
                o.x = acc[i][j + 0] + bv.x;
                o.y = acc[i][j + 1] + bv.y;
                o.z = acc[i][j + 2] + bv.z;
                o.w = acc[i][j + 3] + bv.w;
                if (act) {
                    o.x = fmaxf(o.x, 0.f); o.y = fmaxf(o.y, 0.f);
                    o.z = fmaxf(o.z, 0.f); o.w = fmaxf(o.w, 0.f);
                }
                *(float4*)&Cr[col] = o;
            }
        }
    }
}

// ---------------- edge scatter ----------------
__global__ void k_scatter(const float* __restrict__ h, const int* __restrict__ edge,
                          float* __restrict__ msg, float* __restrict__ cnt) {
    int tid = threadIdx.x;
    int e = blockIdx.x * 2 + (tid >> 7);
    int j = tid & 127;
    int s = edge[e];
    int d = edge[EE + e];
    atomicAdd(&msg[(size_t)d * HH + j], h[(size_t)s * HH + j]);
    if (j == 0) atomicAdd(&cnt[d], 1.0f);
}

__global__ void k_prep(float* __restrict__ msg, const float* __restrict__ cnt) {
    int i = blockIdx.x * 256 + threadIdx.x;
    int n = i >> 7;
    msg[i] = msg[i] / fmaxf(cnt[n], 1.0f);
}

// ---------------- GRU combine ----------------
__global__ void k_combine(const float* __restrict__ gi, const float* __restrict__ gh,
                          float* __restrict__ h) {
    int i = blockIdx.x * 256 + threadIdx.x;
    int n = i >> 7;
    int j = i & 127;
    size_t b = (size_t)n * 384;
    float gir = gi[b + j], giz = gi[b + 128 + j], gin = gi[b + 256 + j];
    float ghr = gh[b + j], ghz = gh[b + 128 + j], ghn = gh[b + 256 + j];
    float hv = h[i];
    float r = 1.f / (1.f + expf(-(gir + ghr)));
    float z = 1.f / (1.f + expf(-(giz + ghz)));
    float nn = tanhf(gin + r * ghn);
    h[i] = (1.f - z) * nn + z * hv;
}

// ---------------- gate scalar ----------------
__global__ void k_gatevec(const float* __restrict__ g1, const float* __restrict__ Wg2,
                          const float* __restrict__ bg2, float* __restrict__ gate) {
    int tid = threadIdx.x;
    int n = blockIdx.x * 4 + (tid >> 6);
    int l = tid & 63;
    const float* gr = g1 + (size_t)n * HH;
    float v = Wg2[l] * gr[l] + Wg2[64 + l] * gr[64 + l];
    #pragma unroll
    for (int o = 32; o > 0; o >>= 1) v += __shfl_down(v, o);
    if (l == 0) gate[n] = v + bg2[0];
}

// ---------------- segment softmax + weighted pool ----------------
__global__ void k_pool(const float* __restrict__ gate, const float* __restrict__ h,
                       float* __restrict__ pooled) {
    int g = blockIdx.x;
    int t = threadIdx.x;  // 0..127
    __shared__ float sg[16];
    if (t < 16) sg[t] = gate[g * 16 + t];
    __syncthreads();
    float mx = -1e30f;
    #pragma unroll
    for (int i = 0; i < 16; ++i) mx = fmaxf(mx, sg[i]);
    float a[16];
    float den = 0.f;
    #pragma unroll
    for (int i = 0; i < 16; ++i) { a[i] = expf(sg[i] - mx); den += a[i]; }
    float inv = 1.f / den;
    float acc = 0.f;
    #pragma unroll
    for (int i = 0; i < 16; ++i)
        acc += a[i] * inv * h[((size_t)(g * 16 + i)) * HH + t];
    pooled[(size_t)g * HH + t] = acc;
}

// ---------------- fp32 -> bf16 hi/lo split ----------------
__global__ void k_cvt_pair(const float* __restrict__ src, unsigned short* __restrict__ hi,
                           unsigned short* __restrict__ lo, int n_valid, int n_total) {
    int i = blockIdx.x * 256 + threadIdx.x;
    if (i >= n_total) return;
    float x = (i < n_valid) ? src[i] : 0.f;
    __hip_bfloat16 h = __float2bfloat16(x);
    float hf = __bfloat162float(h);
    __hip_bfloat16 l = __float2bfloat16(x - hf);
    hi[i] = *reinterpret_cast<unsigned short*>(&h);
    lo[i] = *reinterpret_cast<unsigned short*>(&l);
}

// ---------------- FC GEMM, write-locality version ----------------
// grid (196, 8): block = 256 cols x 512 rows. 4 waves; wave w owns cols
// [c0+w*64, c0+w*64+63] as 4 col-tiles with Wfc hi/lo frags in registers.
// Per 16-row M-tile: MFMA -> stage 16x256 f32 in LDS -> cooperative
// dwordx4 stores, 1KB contiguous per output row per block.
#define LSTR 268
__launch_bounds__(256, 2)
__global__ void k_fc2(const unsigned short* __restrict__ Whi, const unsigned short* __restrict__ Wlo,
                      const unsigned short* __restrict__ phi, const unsigned short* __restrict__ plo,
                      const float* __restrict__ bfc, float* __restrict__ out) {
    __shared__ float ls[16 * LSTR];
    int tid = threadIdx.x;
    int w = tid >> 6, l = tid & 63;
    int c0 = blockIdx.x * 256;
    int mbase = blockIdx.y * 512;
    int lr = l & 15;          // fragment row (A) / col (B) index
    int lk = l >> 4;          // k-group 0..3
    int koff = lk * 8;

    bf16x8 bh[4][4], bl[4][4];
    float bias[4];
    #pragma unroll
    for (int ci = 0; ci < 4; ++ci) {
        int n = c0 + w * 64 + ci * 16 + lr;
        const unsigned short* Wr  = Whi + (size_t)n * HH + koff;
        const unsigned short* Wr2 = Wlo + (size_t)n * HH + koff;
        #pragma unroll
        for (int kc = 0; kc < 4; ++kc) {
            bh[ci][kc] = *(const bf16x8*)(Wr  + kc * 32);
            bl[ci][kc] = *(const bf16x8*)(Wr2 + kc * 32);
        }
        bias[ci] = (n < ITEMS) ? bfc[n] : 0.f;
    }

    int row = tid >> 4;       // store phase: 0..15
    int cg  = tid & 15;

    for (int mt = 0; mt < 32; ++mt) {
        int m0 = mbase + mt * 16;
        const unsigned short* pr  = phi + (size_t)(m0 + lr) * HH + koff;
        const unsigned short* pr2 = plo + (size_t)(m0 + lr) * HH + koff;
        bf16x8 ah[4], al[4];
        #pragma unroll
        for (int kc = 0; kc < 4; ++kc) {
            ah[kc] = *(const bf16x8*)(pr  + kc * 32);
            al[kc] = *(const bf16x8*)(pr2 + kc * 32);
        }
        #pragma unroll
        for (int ci = 0; ci < 4; ++ci) {
            f32x4 acc = {0.f, 0.f, 0.f, 0.f};
            #pragma unroll
            for (int kc = 0; kc < 4; ++kc) {
                acc = __builtin_amdgcn_mfma_f32_16x16x32_bf16(ah[kc], bh[ci][kc], acc, 0, 0, 0);
                acc = __builtin_amdgcn_mfma_f32_16x16x32_bf16(ah[kc], bl[ci][kc], acc, 0, 0, 0);
                acc = __builtin_amdgcn_mfma_f32_16x16x32_bf16(al[kc], bh[ci][kc], acc, 0, 0, 0);
            }
            int col = w * 64 + ci * 16 + lr;
            #pragma unroll
            for (int r = 0; r < 4; ++r)
                ls[(lk * 4 + r) * LSTR + col] = acc[r] + bias[ci];
        }
        __syncthreads();
        #pragma unroll
        for (int i = 0; i < 4; ++i) {
            int c = cg * 4 + i * 64;
            int gc = c0 + c;
            if (gc < ITEMS) {
                float4 v = *(const float4*)&ls[row * LSTR + c];
                *(float4*)&out[(size_t)(m0 + row) * ITEMS + gc] = v;
            }
        }
        __syncthreads();
    }
}

extern "C" void kernel_launch(void* const* d_in, const int* in_sizes, int n_in,
                              void* d_out, int out_size, void* d_ws, size_t ws_size,
                              hipStream_t stream) {
    const int* category = (const int*)d_in[0];
    const int* sub_cat  = (const int*)d_in[1];
    const int* element  = (const int*)d_in[2];
    const int* brand    = (const int*)d_in[3];
    const int* pid      = (const int*)d_in[4];
    const float* price  = (const float*)d_in[5];
    const int* edge     = (const int*)d_in[6];
    const float* ecat   = (const float*)d_in[8];
    const float* esub   = (const float*)d_in[9];
    const float* eel    = (const float*)d_in[10];
    const float* ebr    = (const float*)d_in[11];
    const float* eitem  = (const float*)d_in[12];
    const float* Wm     = (const float*)d_in[13];
    const float* bm     = (const float*)d_in[14];
    const float* W_ih   = (const float*)d_in[15];
    const float* b_ih   = (const float*)d_in[16];
    const float* W_hh   = (const float*)d_in[17];
    const float* b_hh   = (const float*)d_in[18];
    const float* Wg1    = (const float*)d_in[19];
    const float* bg1    = (const float*)d_in[20];
    const float* Wg2    = (const float*)d_in[21];
    const float* bg2    = (const float*)d_in[22];
    const float* Wfc    = (const float*)d_in[23];
    const float* bfc    = (const float*)d_in[24];
    float* out = (float*)d_out;

    // workspace layout (floats)
    const size_t REG = (size_t)NN * 384;
    float* ws = (float*)d_ws;
    float* regionA = ws;                         // X (N*321) then gh (N*384)
    float* regionB = ws + REG;                   // gi (N*384); later bf16 splits
    float* hbuf    = ws + 2 * REG;               // N*128
    float* msg     = hbuf + (size_t)NN * HH;     // N*128 (msg -> m -> g1)
    float* cnt     = msg + (size_t)NN * HH;      // N
    float* gate    = cnt + NN;                   // N
    float* pooled  = gate + NN;                  // G*128

    // bf16 split buffers in regionB (free after k_combine): ~28 MB << 96 MB
    unsigned short* Whi = (unsigned short*)regionB;
    unsigned short* Wlo = Whi + (size_t)NP * HH;
    unsigned short* phi = Wlo + (size_t)NP * HH;
    unsigned short* plo = phi + (size_t)GG * HH;

    hipMemsetAsync(msg, 0, (size_t)NN * HH * sizeof(float), stream);
    hipMemsetAsync(cnt, 0, (size_t)NN * sizeof(float), stream);

    // 1. embedding gather
    k_embed<<<NN / 4, 256, 0, stream>>>(category, sub_cat, element, brand, pid, price,
                                        ecat, esub, eel, ebr, eitem, regionA);
    // 2. h = X @ Wm^T + bm
    gemm_bt<<<dim3(NN / BM, 1), 256, 0, stream>>>(regionA, Wm, bm, hbuf, NN, HH, INF_, 0);
    // 3. scatter-mean
    k_scatter<<<EE / 2, 256, 0, stream>>>(hbuf, edge, msg, cnt);
    k_prep<<<NN * HH / 256, 256, 0, stream>>>(msg, cnt);
    // 4. GRU gemms
    gemm_bt<<<dim3(NN / BM, 3), 256, 0, stream>>>(msg, W_ih, b_ih, regionB, NN, 384, HH, 0);
    gemm_bt<<<dim3(NN / BM, 3), 256, 0, stream>>>(hbuf, W_hh, b_hh, regionA, NN, 384, HH, 0);
    k_combine<<<NN * HH / 256, 256, 0, stream>>>(regionB, regionA, hbuf);
    // 5. gate MLP (g1 -> msg buffer)
    gemm_bt<<<dim3(NN / BM, 1), 256, 0, stream>>>(hbuf, Wg1, bg1, msg, NN, HH, HH, 1);
    k_gatevec<<<NN / 4, 256, 0, stream>>>(msg, Wg2, bg2, gate);
    // 6. segment softmax pooling
    k_pool<<<GG, 128, 0, stream>>>(gate, hbuf, pooled);
    // 7. split-bf16 conversions (regionB free now)
    {
        int ntot = NP * HH;
        k_cvt_pair<<<(ntot + 255) / 256, 256, 0, stream>>>(Wfc, Whi, Wlo, ITEMS * HH, ntot);
        int ptot = GG * HH;
        k_cvt_pair<<<(ptot + 255) / 256, 256, 0, stream>>>(pooled, phi, plo, ptot, ptot);
    }
    // 8. out = pooled @ Wfc^T + bfc via MFMA, write-coalesced
    k_fc2<<<dim3(NP / 256, 8), 256, 0, stream>>>(Whi, Wlo, phi, plo, bfc, out);
}

// Round 4
// 779.650 us; speedup vs baseline: 1.7283x; 1.2277x over previous
//
#include <hip/hip_runtime.h>
#include <hip/hip_bf16.h>
#include <cstdint>
#include <cstddef>

#define NN 65536
#define EE 131072
#define GG 4096
#define HH 128
#define DD 64
#define KP 384        // padded input-feature K (321 -> 384)
#define ITEMS 50000
#define NP 50176      // ITEMS padded to multiple of 256

typedef __attribute__((ext_vector_type(8))) short bf16x8;
typedef __attribute__((ext_vector_type(4))) float f32x4;
typedef unsigned short u16;
typedef __attribute__((ext_vector_type(4))) unsigned short u16x4;

__device__ inline void split2(float x, u16* hi, u16* lo) {
    __hip_bfloat16 h = __float2bfloat16(x);
    float hf = __bfloat162float(h);
    __hip_bfloat16 l = __float2bfloat16(x - hf);
    *hi = *reinterpret_cast<u16*>(&h);
    *lo = *reinterpret_cast<u16*>(&l);
}

// ---------------- embedding gather -> Xpair[N][384] (bf16 hi/lo) ----------------
__global__ void k_embed(const int* __restrict__ cat, const int* __restrict__ sub,
                        const int* __restrict__ el, const int* __restrict__ br,
                        const int* __restrict__ pid, const float* __restrict__ price,
                        const float* __restrict__ ecat, const float* __restrict__ esub,
                        const float* __restrict__ eel, const float* __restrict__ ebr,
                        const float* __restrict__ eitem,
                        u16* __restrict__ Xhi, u16* __restrict__ Xlo) {
    int tid = threadIdx.x;
    int n = blockIdx.x * 4 + (tid >> 6);
    int l = tid & 63;
    u16* xh = Xhi + (size_t)n * KP;
    u16* xl = Xlo + (size_t)n * KP;
    if (l == 0) split2(price[n], xh, xl);
    split2(ecat[(size_t)cat[n] * DD + l], xh + 1 + l,   xl + 1 + l);
    split2(esub[(size_t)sub[n] * DD + l], xh + 65 + l,  xl + 65 + l);
    split2(eel [(size_t)el[n]  * DD + l], xh + 129 + l, xl + 129 + l);
    split2(ebr [(size_t)br[n]  * DD + l], xh + 193 + l, xl + 193 + l);
    split2(eitem[(size_t)pid[n]* DD + l], xh + 257 + l, xl + 257 + l);
    if (l < 63) { xh[321 + l] = 0; xl[321 + l] = 0; }
}

// ---------------- generic fp32 -> bf16 hi/lo split ----------------
__global__ void k_cvt_pair(const float* __restrict__ src, u16* __restrict__ hi,
                           u16* __restrict__ lo, int n_valid, int n_total) {
    int i = blockIdx.x * 256 + threadIdx.x;
    if (i >= n_total) return;
    float x = (i < n_valid) ? src[i] : 0.f;
    split2(x, hi + i, lo + i);
}

// ---------------- Wm (128x321) -> pair padded to (128x384) ----------------
__global__ void k_cvt_wm(const float* __restrict__ Wm, u16* __restrict__ hi,
                         u16* __restrict__ lo) {
    int i = blockIdx.x * 256 + threadIdx.x;   // < 128*384
    int r = i / KP, c = i - r * KP;
    float x = (c < 321) ? Wm[r * 321 + c] : 0.f;
    split2(x, hi + i, lo + i);
}

// ---------------- h = X @ Wm^T + bm  (MFMA, emits f32 + pair) ----------------
#define M1_STR 132
__launch_bounds__(256, 2)
__global__ void k_mlp1(const u16* __restrict__ Xhi, const u16* __restrict__ Xlo,
                       const u16* __restrict__ Whi, const u16* __restrict__ Wlo,
                       const float* __restrict__ bm, float* __restrict__ h,
                       u16* __restrict__ hhi, u16* __restrict__ hlo) {
    __shared__ float ls[128 * M1_STR];
    int tid = threadIdx.x, w = tid >> 6, l = tid & 63;
    int lr = l & 15, lk = l >> 4;
    int m0 = blockIdx.x * 128;
    f32x4 acc[2][8];
    #pragma unroll
    for (int rt = 0; rt < 2; ++rt)
        #pragma unroll
        for (int ci = 0; ci < 8; ++ci) acc[rt][ci] = (f32x4){0.f, 0.f, 0.f, 0.f};

    for (int kc = 0; kc < 12; ++kc) {
        bf16x8 ah[2], al[2];
        #pragma unroll
        for (int rt = 0; rt < 2; ++rt) {
            size_t off = (size_t)(m0 + w * 32 + rt * 16 + lr) * KP + kc * 32 + lk * 8;
            ah[rt] = *(const bf16x8*)(Xhi + off);
            al[rt] = *(const bf16x8*)(Xlo + off);
        }
        #pragma unroll
        for (int ci = 0; ci < 8; ++ci) {
            size_t boff = (size_t)(ci * 16 + lr) * KP + kc * 32 + lk * 8;
            bf16x8 bh = *(const bf16x8*)(Whi + boff);
            bf16x8 bl = *(const bf16x8*)(Wlo + boff);
            #pragma unroll
            for (int rt = 0; rt < 2; ++rt) {
                acc[rt][ci] = __builtin_amdgcn_mfma_f32_16x16x32_bf16(ah[rt], bh, acc[rt][ci], 0, 0, 0);
                acc[rt][ci] = __builtin_amdgcn_mfma_f32_16x16x32_bf16(ah[rt], bl, acc[rt][ci], 0, 0, 0);
                acc[rt][ci] = __builtin_amdgcn_mfma_f32_16x16x32_bf16(al[rt], bh, acc[rt][ci], 0, 0, 0);
            }
        }
    }
    #pragma unroll
    for (int rt = 0; rt < 2; ++rt)
        #pragma unroll
        for (int ci = 0; ci < 8; ++ci) {
            int col = ci * 16 + lr;
            float bv = bm[col];
            #pragma unroll
            for (int q = 0; q < 4; ++q)
                ls[(w * 32 + rt * 16 + lk * 4 + q) * M1_STR + col] = acc[rt][ci][q] + bv;
        }
    __syncthreads();
    int row = tid >> 1, cb = (tid & 1) * 64;
    float* hd = h + (size_t)(m0 + row) * HH + cb;
    u16* hh = hhi + (size_t)(m0 + row) * HH + cb;
    u16* hl = hlo + (size_t)(m0 + row) * HH + cb;
    #pragma unroll
    for (int i = 0; i < 64; i += 4) {
        float4 v = *(const float4*)&ls[row * M1_STR + cb + i];
        *(float4*)(hd + i) = v;
        u16x4 vh, vl;
        split2(v.x, (u16*)&vh + 0, (u16*)&vl + 0);
        split2(v.y, (u16*)&vh + 1, (u16*)&vl + 1);
        split2(v.z, (u16*)&vh + 2, (u16*)&vl + 2);
        split2(v.w, (u16*)&vh + 3, (u16*)&vl + 3);
        *(u16x4*)(hh + i) = vh;
        *(u16x4*)(hl + i) = vl;
    }
}

// ---------------- edge scatter: msg[dst] += h[src]; cnt[dst] += 1 ----------------
__global__ void k_scatter(const float* __restrict__ h, const int* __restrict__ edge,
                          float* __restrict__ msg, float* __restrict__ cnt) {
    int j = threadIdx.x & 127;
    int eo = threadIdx.x >> 7;
    int e0 = blockIdx.x * 16;
    #pragma unroll
    for (int it = 0; it < 8; ++it) {
        int e = e0 + it * 2 + eo;
        int s = edge[e];
        int d = edge[EE + e];
        atomicAdd(&msg[(size_t)d * HH + j], h[(size_t)s * HH + j]);
        if (j == 0) atomicAdd(&cnt[d], 1.0f);
    }
}

// ---------------- m = msg / max(cnt,1)  -> pair ----------------
__global__ void k_prep(const float* __restrict__ msg, const float* __restrict__ cnt,
                       u16* __restrict__ mhi, u16* __restrict__ mlo) {
    int i = blockIdx.x * 256 + threadIdx.x;
    int n = i >> 7;
    float x = msg[i] / fmaxf(cnt[n], 1.0f);
    split2(x, mhi + i, mlo + i);
}

// ---------------- fused GRU: both GEMMs + gates, in-register ----------------
// BM=32 rows/block, 4 waves; wave w owns j-cols [w*32, w*32+32).
// acc[g][ct][rt]: g: 0-2 = gi r/z/n (A=m, W=W_ih), 3-5 = gh r/z/n (A=h, W=W_hh).
#define GRU_STR 136
__launch_bounds__(256, 2)
__global__ void k_gru(const u16* __restrict__ mhi, const u16* __restrict__ mlo,
                      const u16* __restrict__ hhi_in, const u16* __restrict__ hlo_in,
                      const u16* __restrict__ Wihh, const u16* __restrict__ Wihl,
                      const u16* __restrict__ Whhh, const u16* __restrict__ Whhl,
                      const float* __restrict__ b_ih, const float* __restrict__ b_hh,
                      float* __restrict__ h, u16* __restrict__ hhi, u16* __restrict__ hlo) {
    __shared__ float ls[32 * GRU_STR];
    int tid = threadIdx.x, w = tid >> 6, l = tid & 63;
    int lr = l & 15, lk = l >> 4;
    int m0 = blockIdx.x * 32;
    f32x4 acc[6][2][2];
    #pragma unroll
    for (int g = 0; g < 6; ++g)
        #pragma unroll
        for (int ct = 0; ct < 2; ++ct)
            #pragma unroll
            for (int rt = 0; rt < 2; ++rt) acc[g][ct][rt] = (f32x4){0.f, 0.f, 0.f, 0.f};

    for (int kc = 0; kc < 4; ++kc) {
        bf16x8 amh[2], aml[2], ahh[2], ahl[2];
        #pragma unroll
        for (int rt = 0; rt < 2; ++rt) {
            size_t off = (size_t)(m0 + rt * 16 + lr) * HH + kc * 32 + lk * 8;
            amh[rt] = *(const bf16x8*)(mhi + off);
            aml[rt] = *(const bf16x8*)(mlo + off);
            ahh[rt] = *(const bf16x8*)(hhi_in + off);
            ahl[rt] = *(const bf16x8*)(hlo_in + off);
        }
        #pragma unroll
        for (int g = 0; g < 6; ++g) {
            const u16* WH = (g < 3) ? Wihh : Whhh;
            const u16* WL = (g < 3) ? Wihl : Whhl;
            int gb = (g % 3) * HH;
            #pragma unroll
            for (int ct = 0; ct < 2; ++ct) {
                size_t boff = (size_t)(gb + w * 32 + ct * 16 + lr) * HH + kc * 32 + lk * 8;
                bf16x8 bh = *(const bf16x8*)(WH + boff);
                bf16x8 bl = *(const bf16x8*)(WL + boff);
                #pragma unroll
                for (int rt = 0; rt < 2; ++rt) {
                    bf16x8 ah = (g < 3) ? amh[rt] : ahh[rt];
                    bf16x8 al = (g < 3) ? aml[rt] : ahl[rt];
                    acc[g][ct][rt] = __builtin_amdgcn_mfma_f32_16x16x32_bf16(ah, bh, acc[g][ct][rt], 0, 0, 0);
                    acc[g][ct][rt] = __builtin_amdgcn_mfma_f32_16x16x32_bf16(ah, bl, acc[g][ct][rt], 0, 0, 0);
                    acc[g][ct][rt] = __builtin_amdgcn_mfma_f32_16x16x32_bf16(al, bh, acc[g][ct][rt], 0, 0, 0);
                }
            }
        }
    }
    #pragma unroll
    for (int ct = 0; ct < 2; ++ct) {
        int col = w * 32 + ct * 16 + lr;
        float bir = b_ih[col], biz = b_ih[HH + col], bin = b_ih[2 * HH + col];
        float bhr = b_hh[col], bhz = b_hh[HH + col], bhn = b_hh[2 * HH + col];
        #pragma unroll
        for (int rt = 0; rt < 2; ++rt)
            #pragma unroll
            for (int q = 0; q < 4; ++q) {
                int rl = rt * 16 + lk * 4 + q;
                float gir = acc[0][ct][rt][q] + bir;
                float giz = acc[1][ct][rt][q] + biz;
                float gin = acc[2][ct][rt][q] + bin;
                float ghr = acc[3][ct][rt][q] + bhr;
                float ghz = acc[4][ct][rt][q] + bhz;
                float ghn = acc[5][ct][rt][q] + bhn;
                float hv = h[(size_t)(m0 + rl) * HH + col];
                float r = 1.f / (1.f + expf(-(gir + ghr)));
                float z = 1.f / (1.f + expf(-(giz + ghz)));
                float nn = tanhf(gin + r * ghn);
                ls[rl * GRU_STR + col] = (1.f - z) * nn + z * hv;
            }
    }
    __syncthreads();
    int row = tid >> 3, cb = (tid & 7) * 16;
    float* hd = h + (size_t)(m0 + row) * HH + cb;
    u16* hh = hhi + (size_t)(m0 + row) * HH + cb;
    u16* hl = hlo + (size_t)(m0 + row) * HH + cb;
    #pragma unroll
    for (int i = 0; i < 16; i += 4) {
        float4 v = *(const float4*)&ls[row * GRU_STR + cb + i];
        *(float4*)(hd + i) = v;
        u16x4 vh, vl;
        split2(v.x, (u16*)&vh + 0, (u16*)&vl + 0);
        split2(v.y, (u16*)&vh + 1, (u16*)&vl + 1);
        split2(v.z, (u16*)&vh + 2, (u16*)&vl + 2);
        split2(v.w, (u16*)&vh + 3, (u16*)&vl + 3);
        *(u16x4*)(hh + i) = vh;
        *(u16x4*)(hl + i) = vl;
    }
}

// ---------------- fused gate: gate = relu(h@Wg1^T+bg1) . Wg2 + bg2 ----------------
__launch_bounds__(256, 2)
__global__ void k_gate(const u16* __restrict__ hhi, const u16* __restrict__ hlo,
                       const u16* __restrict__ Ghi, const u16* __restrict__ Glo,
                       const float* __restrict__ bg1, const float* __restrict__ Wg2,
                       const float* __restrict__ bg2, float* __restrict__ gate) {
    int tid = threadIdx.x, w = tid >> 6, l = tid & 63;
    int lr = l & 15, lk = l >> 4;
    int m0 = blockIdx.x * 128;
    f32x4 acc[2][8];
    #pragma unroll
    for (int rt = 0; rt < 2; ++rt)
        #pragma unroll
        for (int ci = 0; ci < 8; ++ci) acc[rt][ci] = (f32x4){0.f, 0.f, 0.f, 0.f};

    for (int kc = 0; kc < 4; ++kc) {
        bf16x8 ah[2], al[2];
        #pragma unroll
        for (int rt = 0; rt < 2; ++rt) {
            size_t off = (size_t)(m0 + w * 32 + rt * 16 + lr) * HH + kc * 32 + lk * 8;
            ah[rt] = *(const bf16x8*)(hhi + off);
            al[rt] = *(const bf16x8*)(hlo + off);
        }
        #pragma unroll
        for (int ci = 0; ci < 8; ++ci) {
            size_t boff = (size_t)(ci * 16 + lr) * HH + kc * 32 + lk * 8;
            bf16x8 bh = *(const bf16x8*)(Ghi + boff);
            bf16x8 bl = *(const bf16x8*)(Glo + boff);
            #pragma unroll
            for (int rt = 0; rt < 2; ++rt) {
                acc[rt][ci] = __builtin_amdgcn_mfma_f32_16x16x32_bf16(ah[rt], bh, acc[rt][ci], 0, 0, 0);
                acc[rt][ci] = __builtin_amdgcn_mfma_f32_16x16x32_bf16(ah[rt], bl, acc[rt][ci], 0, 0, 0);
                acc[rt][ci] = __builtin_amdgcn_mfma_f32_16x16x32_bf16(al[rt], bh, acc[rt][ci], 0, 0, 0);
            }
        }
    }
    float part[2][4] = {};
    #pragma unroll
    for (int ci = 0; ci < 8; ++ci) {
        int col = ci * 16 + lr;
        float wv = Wg2[col], bb = bg1[col];
        #pragma unroll
        for (int rt = 0; rt < 2; ++rt)
            #pragma unroll
            for (int q = 0; q < 4; ++q)
                part[rt][q] += fmaxf(acc[rt][ci][q] + bb, 0.f) * wv;
    }
    #pragma unroll
    for (int rt = 0; rt < 2; ++rt)
        #pragma unroll
        for (int q = 0; q < 4; ++q) {
            float v = part[rt][q];
            v += __shfl_xor(v, 1);
            v += __shfl_xor(v, 2);
            v += __shfl_xor(v, 4);
            v += __shfl_xor(v, 8);
            part[rt][q] = v;
        }
    if (lr == 0) {
        float b2 = bg2[0];
        #pragma unroll
        for (int rt = 0; rt < 2; ++rt)
            #pragma unroll
            for (int q = 0; q < 4; ++q)
                gate[m0 + w * 32 + rt * 16 + lk * 4 + q] = part[rt][q] + b2;
    }
}

// ---------------- segment softmax + weighted pool ----------------
__global__ void k_pool(const float* __restrict__ gate, const float* __restrict__ h,
                       float* __restrict__ pooled) {
    int g = blockIdx.x;
    int t = threadIdx.x;  // 0..127
    __shared__ float sg[16];
    if (t < 16) sg[t] = gate[g * 16 + t];
    __syncthreads();
    float mx = -1e30f;
    #pragma unroll
    for (int i = 0; i < 16; ++i) mx = fmaxf(mx, sg[i]);
    float a[16];
    float den = 0.f;
    #pragma unroll
    for (int i = 0; i < 16; ++i) { a[i] = expf(sg[i] - mx); den += a[i]; }
    float inv = 1.f / den;
    float acc = 0.f;
    #pragma unroll
    for (int i = 0; i < 16; ++i)
        acc += a[i] * inv * h[((size_t)(g * 16 + i)) * HH + t];
    pooled[(size_t)g * HH + t] = acc;
}

// ---------------- FC: double-buffered LDS, wave-contiguous 1KB stores ----------------
#define FC_STR 260
__launch_bounds__(256, 2)
__global__ void k_fc3(const u16* __restrict__ Whi, const u16* __restrict__ Wlo,
                      const u16* __restrict__ phi, const u16* __restrict__ plo,
                      const float* __restrict__ bfc, float* __restrict__ out) {
    __shared__ float ls[2][32][FC_STR];
    int tid = threadIdx.x, w = tid >> 6, l = tid & 63;
    int lr = l & 15, lk = l >> 4;
    int c0 = blockIdx.x * 256;
    int mbase = blockIdx.y * 512;

    bf16x8 bh[4][4], bl[4][4];
    float bias[4];
    #pragma unroll
    for (int ci = 0; ci < 4; ++ci) {
        int n = c0 + w * 64 + ci * 16 + lr;
        #pragma unroll
        for (int kc = 0; kc < 4; ++kc) {
            size_t off = (size_t)n * HH + kc * 32 + lk * 8;
            bh[ci][kc] = *(const bf16x8*)(Whi + off);
            bl[ci][kc] = *(const bf16x8*)(Wlo + off);
        }
        bias[ci] = (n < ITEMS) ? bfc[n] : 0.f;
    }

    auto STAGE = [&](int t, int b) {
        int m0 = mbase + t * 32;
        #pragma unroll
        for (int rt = 0; rt < 2; ++rt) {
            size_t aoff = (size_t)(m0 + rt * 16 + lr) * HH + lk * 8;
            bf16x8 ah[4], al[4];
            #pragma unroll
            for (int kc = 0; kc < 4; ++kc) {
                ah[kc] = *(const bf16x8*)(phi + aoff + kc * 32);
                al[kc] = *(const bf16x8*)(plo + aoff + kc * 32);
            }
            #pragma unroll
            for (int ci = 0; ci < 4; ++ci) {
                f32x4 acc = (f32x4){0.f, 0.f, 0.f, 0.f};
                #pragma unroll
                for (int kc = 0; kc < 4; ++kc) {
                    acc = __builtin_amdgcn_mfma_f32_16x16x32_bf16(ah[kc], bh[ci][kc], acc, 0, 0, 0);
                    acc = __builtin_amdgcn_mfma_f32_16x16x32_bf16(ah[kc], bl[ci][kc], acc, 0, 0, 0);
                    acc = __builtin_amdgcn_mfma_f32_16x16x32_bf16(al[kc], bh[ci][kc], acc, 0, 0, 0);
                }
                #pragma unroll
                for (int q = 0; q < 4; ++q)
                    ls[b][rt * 16 + lk * 4 + q][w * 64 + ci * 16 + lr] = acc[q] + bias[ci];
            }
        }
    };
    auto FLUSH = [&](int t, int b) {
        int m0 = mbase + t * 32;
        int gc = c0 + l * 4;
        bool ok = (gc < ITEMS);
        #pragma unroll
        for (int i = 0; i < 8; ++i) {
            int row = i * 4 + w;
            if (ok) {
                float4 v = *(const float4*)&ls[b][row][l * 4];
                *(float4*)&out[(size_t)(m0 + row) * ITEMS + gc] = v;
            }
        }
    };

    STAGE(0, 0);
    __syncthreads();
    for (int t = 1; t < 16; ++t) {
        FLUSH(t - 1, (t - 1) & 1);
        STAGE(t, t & 1);
        __syncthreads();
    }
    FLUSH(15, 1);
}

extern "C" void kernel_launch(void* const* d_in, const int* in_sizes, int n_in,
                              void* d_out, int out_size, void* d_ws, size_t ws_size,
                              hipStream_t stream) {
    const int* category = (const int*)d_in[0];
    const int* sub_cat  = (const int*)d_in[1];
    const int* element  = (const int*)d_in[2];
    const int* brand    = (const int*)d_in[3];
    const int* pid      = (const int*)d_in[4];
    const float* price  = (const float*)d_in[5];
    const int* edge     = (const int*)d_in[6];
    const float* ecat   = (const float*)d_in[8];
    const float* esub   = (const float*)d_in[9];
    const float* eel    = (const float*)d_in[10];
    const float* ebr    = (const float*)d_in[11];
    const float* eitem  = (const float*)d_in[12];
    const float* Wm     = (const float*)d_in[13];
    const float* bm     = (const float*)d_in[14];
    const float* W_ih   = (const float*)d_in[15];
    const float* b_ih   = (const float*)d_in[16];
    const float* W_hh   = (const float*)d_in[17];
    const float* b_hh   = (const float*)d_in[18];
    const float* Wg1    = (const float*)d_in[19];
    const float* bg1    = (const float*)d_in[20];
    const float* Wg2    = (const float*)d_in[21];
    const float* bg2    = (const float*)d_in[22];
    const float* Wfc    = (const float*)d_in[23];
    const float* bfc    = (const float*)d_in[24];
    float* out = (float*)d_out;

    // ---- workspace carve-up (bytes), 256B-aligned regions ----
    char* p = (char*)d_ws;
    auto alloc = [&](size_t bytes) { char* r = p; p += (bytes + 255) & ~(size_t)255; return r; };
    u16* Xhi   = (u16*)alloc((size_t)NN * KP * 2);
    u16* Xlo   = (u16*)alloc((size_t)NN * KP * 2);
    float* h   = (float*)alloc((size_t)NN * HH * 4);
    u16* hhi   = (u16*)alloc((size_t)NN * HH * 2);
    u16* hlo   = (u16*)alloc((size_t)NN * HH * 2);
    float* msg = (float*)alloc((size_t)NN * HH * 4);
    float* cnt = (float*)alloc((size_t)NN * 4);
    u16* mhi   = (u16*)alloc((size_t)NN * HH * 2);
    u16* mlo   = (u16*)alloc((size_t)NN * HH * 2);
    float* gate   = (float*)alloc((size_t)NN * 4);
    float* pooled = (float*)alloc((size_t)GG * HH * 4);
    u16* phi   = (u16*)alloc((size_t)GG * HH * 2);
    u16* plo   = (u16*)alloc((size_t)GG * HH * 2);
    u16* Wmhi  = (u16*)alloc((size_t)HH * KP * 2);
    u16* Wmlo  = (u16*)alloc((size_t)HH * KP * 2);
    u16* Wihhi = (u16*)alloc((size_t)3 * HH * HH * 2);
    u16* Wihlo = (u16*)alloc((size_t)3 * HH * HH * 2);
    u16* Whhhi = (u16*)alloc((size_t)3 * HH * HH * 2);
    u16* Whhlo = (u16*)alloc((size_t)3 * HH * HH * 2);
    u16* Wg1hi = (u16*)alloc((size_t)HH * HH * 2);
    u16* Wg1lo = (u16*)alloc((size_t)HH * HH * 2);
    u16* Wfchi = (u16*)alloc((size_t)NP * HH * 2);
    u16* Wfclo = (u16*)alloc((size_t)NP * HH * 2);

    hipMemsetAsync(msg, 0, (size_t)NN * HH * sizeof(float), stream);
    hipMemsetAsync(cnt, 0, (size_t)NN * sizeof(float), stream);

    // weight conversions (independent of activations)
    k_cvt_wm<<<(HH * KP + 255) / 256, 256, 0, stream>>>(Wm, Wmhi, Wmlo);
    k_cvt_pair<<<(3 * HH * HH + 255) / 256, 256, 0, stream>>>(W_ih, Wihhi, Wihlo, 3 * HH * HH, 3 * HH * HH);
    k_cvt_pair<<<(3 * HH * HH + 255) / 256, 256, 0, stream>>>(W_hh, Whhhi, Whhlo, 3 * HH * HH, 3 * HH * HH);
    k_cvt_pair<<<(HH * HH + 255) / 256, 256, 0, stream>>>(Wg1, Wg1hi, Wg1lo, HH * HH, HH * HH);
    k_cvt_pair<<<(NP * HH + 255) / 256, 256, 0, stream>>>(Wfc, Wfchi, Wfclo, ITEMS * HH, NP * HH);

    // 1. embedding gather -> X pair
    k_embed<<<NN / 4, 256, 0, stream>>>(category, sub_cat, element, brand, pid, price,
                                        ecat, esub, eel, ebr, eitem, Xhi, Xlo);
    // 2. h = X @ Wm^T + bm
    k_mlp1<<<NN / 128, 256, 0, stream>>>(Xhi, Xlo, Wmhi, Wmlo, bm, h, hhi, hlo);
    // 3. scatter-mean -> m pair
    k_scatter<<<EE / 16, 256, 0, stream>>>(h, edge, msg, cnt);
    k_prep<<<NN * HH / 256, 256, 0, stream>>>(msg, cnt, mhi, mlo);
    // 4. fused GRU (updates h, hhi, hlo in place)
    k_gru<<<NN / 32, 256, 0, stream>>>(mhi, mlo, hhi, hlo, Wihhi, Wihlo, Whhhi, Whhlo,
                                       b_ih, b_hh, h, hhi, hlo);
    // 5. fused gate MLP
    k_gate<<<NN / 128, 256, 0, stream>>>(hhi, hlo, Wg1hi, Wg1lo, bg1, Wg2, bg2, gate);
    // 6. segment softmax pooling
    k_pool<<<GG, 128, 0, stream>>>(gate, h, pooled);
    // 7. pooled -> pair
    k_cvt_pair<<<(GG * HH + 255) / 256, 256, 0, stream>>>(pooled, phi, plo, GG * HH, GG * HH);
    // 8. out = pooled @ Wfc^T + bfc
    k_fc3<<<dim3(NP / 256, GG / 512), 256, 0, stream>>>(Wfchi, Wfclo, phi, plo, bfc, out);
}